// Round 1
// baseline (456.810 us; speedup 1.0000x reference)
//
#include <hip/hip_runtime.h>
#include <math.h>

#define B_ 4
#define C_ 64
#define L_ 4096
#define N_ 100000
#define P_ (B_ * N_)
#define NEG_SLOPE 0.2f

// ---------- kernel 1: transpose feat (B,C,L) -> (B,L,C) ----------
__global__ void transpose_feat(const float* __restrict__ src, float* __restrict__ dst) {
    __shared__ float tile[64][65];
    const int b  = blockIdx.y;
    const int l0 = blockIdx.x * 64;
    const int tx = threadIdx.x & 63;
    const int ty = threadIdx.x >> 6;   // 0..3 (256 threads)
    const size_t base = (size_t)b * C_ * L_;
    #pragma unroll
    for (int cc = ty; cc < 64; cc += 4)
        tile[cc][tx] = src[base + (size_t)cc * L_ + l0 + tx];
    __syncthreads();
    #pragma unroll
    for (int ll = ty; ll < 64; ll += 4)
        dst[base + (size_t)(l0 + ll) * C_ + tx] = tile[tx][ll];
}

// ---------- kernel 2: one thread per point ----------
__global__ __launch_bounds__(128) void deform_main(
    const float* __restrict__ featT,
    const float* __restrict__ coords,
    const float* __restrict__ W1, const float* __restrict__ b1,
    const float* __restrict__ Wr, const float* __restrict__ br,
    const float* __restrict__ W2, const float* __restrict__ b2,
    float* __restrict__ out)
{
    // per-thread 65-float scratch slot; stride 65 -> bank (tid+i)%32, 2 lanes/bank = conflict-free
    __shared__ float scratch[128 * 65];
    const int tid = threadIdx.x;
    const int p = blockIdx.x * 128 + tid;
    if (p >= P_) return;
    float* myslot = scratch + tid * 65;

    const int b = p / N_;
    const float cx = coords[p];

    // ---- anchor sample position ----
    float xp = (cx + 1.0f) * 0.5f * (float)(L_ - 1);
    xp = fminf(fmaxf(xp, 0.0f), (float)(L_ - 1));
    float x0f = floorf(xp);
    float w = xp - x0f;
    int i0 = (int)x0f;
    int i1 = min(i0 + 1, L_ - 1);
    const float* f0p = featT + (((size_t)b * L_ + i0) << 6);
    const float* f1p = featT + (((size_t)b * L_ + i1) << 6);

    // ---- layer 1: h = router_in @ W1 + b1, rank-1 updates fused with the gather ----
    float h[64];
    #pragma unroll
    for (int j = 0; j < 64; ++j) h[j] = b1[j];

    #pragma unroll 1
    for (int c0 = 0; c0 < 64; c0 += 4) {
        const float4 a0 = *reinterpret_cast<const float4*>(f0p + c0);
        const float4 a1 = *reinterpret_cast<const float4*>(f1p + c0);
        float xv0 = fmaf(w, a1.x - a0.x, a0.x);
        float xv1 = fmaf(w, a1.y - a0.y, a0.y);
        float xv2 = fmaf(w, a1.z - a0.z, a0.z);
        float xv3 = fmaf(w, a1.w - a0.w, a0.w);
        const float* Wrow = W1 + c0 * 64;   // uniform address -> s_load
        #pragma unroll
        for (int j = 0; j < 64; ++j) h[j] = fmaf(xv0, Wrow[j], h[j]);
        #pragma unroll
        for (int j = 0; j < 64; ++j) h[j] = fmaf(xv1, Wrow[64 + j], h[j]);
        #pragma unroll
        for (int j = 0; j < 64; ++j) h[j] = fmaf(xv2, Wrow[128 + j], h[j]);
        #pragma unroll
        for (int j = 0; j < 64; ++j) h[j] = fmaf(xv3, Wrow[192 + j], h[j]);
    }
    {
        const float* Wlast = W1 + 64 * 64;  // row for the cx input
        #pragma unroll
        for (int j = 0; j < 64; ++j) h[j] = fmaf(cx, Wlast[j], h[j]);
    }

    // ---- leaky -> a; stage a in own LDS slot; init residual accumulator ----
    float g[64];
    #pragma unroll
    for (int j = 0; j < 64; ++j) {
        float aj = h[j] >= 0.0f ? h[j] : NEG_SLOPE * h[j];
        myslot[j] = aj;
        g[j] = aj + br[j];
    }

    // ---- residual: g = leaky(a + a@Wr + br) ----
    #pragma unroll 1
    for (int i = 0; i < 64; ++i) {
        const float ai = myslot[i];         // ds_read_b32, conflict-free
        const float* Wrow = Wr + i * 64;
        #pragma unroll
        for (int j = 0; j < 64; ++j) g[j] = fmaf(ai, Wrow[j], g[j]);
    }
    #pragma unroll
    for (int j = 0; j < 64; ++j) g[j] = g[j] >= 0.0f ? g[j] : NEG_SLOPE * g[j];

    // ---- layer 3: 64 -> 10 (g static in regs, fully unrolled) ----
    float o[10];
    #pragma unroll
    for (int k = 0; k < 10; ++k) o[k] = b2[k];
    #pragma unroll
    for (int i = 0; i < 64; ++i) {
        #pragma unroll
        for (int k = 0; k < 10; ++k) o[k] = fmaf(g[i], W2[i * 10 + k], o[k]);
    }

    // ---- offsets (tanh) and softmax weights ----
    const float maxoff = 6.0f / (float)L_;
    float offs[5], pw[5];
    #pragma unroll
    for (int k = 0; k < 5; ++k) {
        float ax = fabsf(o[k]);
        float t  = __expf(-2.0f * ax);      // stable tanh
        float th = (1.0f - t) / (1.0f + t);
        offs[k] = copysignf(th, o[k]) * maxoff;
    }
    float m = o[5];
    #pragma unroll
    for (int k = 6; k < 10; ++k) m = fmaxf(m, o[k]);
    float s = 0.0f;
    #pragma unroll
    for (int k = 0; k < 5; ++k) { pw[k] = __expf(o[5 + k] - m); s += pw[k]; }
    const float inv = 1.0f / s;

    // ---- deformed sampling + weighted aggregation ----
    float acc[64];
    #pragma unroll
    for (int c = 0; c < 64; ++c) acc[c] = 0.0f;

    #pragma unroll
    for (int k = 0; k < 5; ++k) {
        float dx = cx + offs[k];
        float xq = (dx + 1.0f) * 0.5f * (float)(L_ - 1);
        xq = fminf(fmaxf(xq, 0.0f), (float)(L_ - 1));
        float xq0 = floorf(xq);
        float wq = xq - xq0;
        int j0 = (int)xq0;
        int j1 = min(j0 + 1, L_ - 1);
        const float* q0 = featT + (((size_t)b * L_ + j0) << 6);
        const float* q1 = featT + (((size_t)b * L_ + j1) << 6);
        const float wk = pw[k] * inv;
        #pragma unroll
        for (int c0 = 0; c0 < 64; c0 += 4) {
            const float4 a0 = *reinterpret_cast<const float4*>(q0 + c0);
            const float4 a1 = *reinterpret_cast<const float4*>(q1 + c0);
            acc[c0 + 0] = fmaf(wk, fmaf(wq, a1.x - a0.x, a0.x), acc[c0 + 0]);
            acc[c0 + 1] = fmaf(wk, fmaf(wq, a1.y - a0.y, a0.y), acc[c0 + 1]);
            acc[c0 + 2] = fmaf(wk, fmaf(wq, a1.z - a0.z, a0.z), acc[c0 + 2]);
            acc[c0 + 3] = fmaf(wk, fmaf(wq, a1.w - a0.w, a0.w), acc[c0 + 3]);
        }
    }

    // ---- store (B,N,C): contiguous 256B per thread ----
    float* op = out + ((size_t)p << 6);
    #pragma unroll
    for (int c0 = 0; c0 < 64; c0 += 4) {
        float4 v = make_float4(acc[c0], acc[c0 + 1], acc[c0 + 2], acc[c0 + 3]);
        *reinterpret_cast<float4*>(op + c0) = v;
    }
}

extern "C" void kernel_launch(void* const* d_in, const int* in_sizes, int n_in,
                              void* d_out, int out_size, void* d_ws, size_t ws_size,
                              hipStream_t stream) {
    const float* feat   = (const float*)d_in[0];
    const float* coords = (const float*)d_in[1];
    const float* W1 = (const float*)d_in[2];
    const float* b1 = (const float*)d_in[3];
    const float* Wr = (const float*)d_in[4];
    const float* br = (const float*)d_in[5];
    const float* W2 = (const float*)d_in[6];
    const float* b2 = (const float*)d_in[7];
    float* out   = (float*)d_out;
    float* featT = (float*)d_ws;   // needs 4*4096*64*4 = 4 MiB

    hipLaunchKernelGGL(transpose_feat, dim3(L_ / 64, B_), dim3(256), 0, stream,
                       feat, featT);
    hipLaunchKernelGGL(deform_main, dim3(P_ / 128), dim3(128), 0, stream,
                       featT, coords, W1, b1, Wr, br, W2, b2, out);
}

// Round 2
// 284.825 us; speedup vs baseline: 1.6038x; 1.6038x over previous
//
#include <hip/hip_runtime.h>
#include <hip/hip_fp16.h>
#include <math.h>

typedef _Float16 f16;
typedef f16 f16x8 __attribute__((ext_vector_type(8)));
typedef float f32x4 __attribute__((ext_vector_type(4)));

#define B_ 4
#define C_ 64
#define L_ 4096
#define N_ 100000
#define P_ (B_ * N_)
#define NEG 0.2f

static __device__ __forceinline__ f32x4 mfma16(f16x8 a, f16x8 b, f32x4 c) {
    return __builtin_amdgcn_mfma_f32_16x16x32_f16(a, b, c, 0, 0, 0);
}

// ---------- kernel 1: transpose feat (B,C,L) -> (B,L,C) ----------
__global__ void transpose_feat(const float* __restrict__ src, float* __restrict__ dst) {
    __shared__ float tile[64][65];
    const int b  = blockIdx.y;
    const int l0 = blockIdx.x * 64;
    const int tx = threadIdx.x & 63;
    const int ty = threadIdx.x >> 6;   // 0..3
    const size_t base = (size_t)b * C_ * L_;
    #pragma unroll
    for (int cc = ty; cc < 64; cc += 4)
        tile[cc][tx] = src[base + (size_t)cc * L_ + l0 + tx];
    __syncthreads();
    #pragma unroll
    for (int ll = ty; ll < 64; ll += 4)
        dst[base + (size_t)(l0 + ll) * C_ + tx] = tile[tx][ll];
}

// ---------- kernel 2: pack W1/Wr/W2 into per-lane f16 MFMA B-fragments ----------
// frag layout: idx = ((nt*2+ks)*64 + lane)*8 + e  holds  W[k = ks*32+(lane>>4)*8+e][c = nt*16+(lane&15)]
__global__ void pack_weights(const float* __restrict__ W1, const float* __restrict__ Wr,
                             const float* __restrict__ W2,
                             f16* __restrict__ W1f, f16* __restrict__ Wrf, f16* __restrict__ W2f) {
    int i = blockIdx.x * 256 + threadIdx.x;
    if (i < 4096) {
        int e = i & 7, lane = (i >> 3) & 63, ks = (i >> 9) & 1, nt = i >> 10;
        int k = ks * 32 + (lane >> 4) * 8 + e;
        int c = nt * 16 + (lane & 15);
        W1f[i] = (f16)W1[k * 64 + c];
        Wrf[i] = (f16)Wr[k * 64 + c];
    }
    if (i < 1024) {                       // W2 padded 64x10 -> 64x16
        int e = i & 7, lane = (i >> 3) & 63, ks = (i >> 9) & 1;
        int k = ks * 32 + (lane >> 4) * 8 + e;
        int c = lane & 15;
        W2f[i] = (c < 10) ? (f16)W2[k * 10 + c] : (f16)0.0f;
    }
}

// ---------- kernel 3: fused MLP (MFMA) + deformable sampling ----------
// one wave = 16 points. A-layout: lane -> row r=l&15, k=(l>>4)*8+e.
// C-layout (HW-verified): lane -> col=l&15, rows=(l>>4)*4+reg.
__global__ __launch_bounds__(256, 4) void deform_mfma(
    const float* __restrict__ featT, const float* __restrict__ coords,
    const f16* __restrict__ W1f, const f16* __restrict__ Wrf, const f16* __restrict__ W2f,
    const float* __restrict__ W1, const float* __restrict__ b1,
    const float* __restrict__ br, const float* __restrict__ b2,
    float* __restrict__ out)
{
    __shared__ __align__(16) f16 a_tile[4][16][72];   // per-wave staging, stride 72 halves = 144 B
    __shared__ float offs_t[4][16][5];
    __shared__ float wk_t[4][16][5];

    const int tid = threadIdx.x;
    const int wv  = tid >> 6;
    const int l   = tid & 63;
    const int r   = l & 15;          // A-role point row / agg point row
    const int q   = l >> 4;          // A-role k-group / agg channel quarter
    const int col = l & 15;          // C-role column
    const int p0  = (blockIdx.x * 4 + wv) * 16;
    const int p   = p0 + r;
    const int b   = p / N_;

    // ---- this lane's point position (anchor) ----
    const float cx = coords[p];
    float xp = fminf(fmaxf((cx + 1.0f) * 0.5f * 4095.0f, 0.0f), 4095.0f);
    float x0f = floorf(xp);
    float w = xp - x0f;
    int i0 = (int)x0f;
    int i1 = min(i0 + 1, 4095);
    const float* f0p = featT + (((size_t)b * L_ + i0) << 6);
    const float* f1p = featT + (((size_t)b * L_ + i1) << 6);

    // ---- W1 fragments (global, L2-hot) ----
    const f16x8* W1p = (const f16x8*)W1f;
    f16x8 wb1[4][2];
    #pragma unroll
    for (int nt = 0; nt < 4; ++nt)
        #pragma unroll
        for (int ks = 0; ks < 2; ++ks)
            wb1[nt][ks] = W1p[(nt * 2 + ks) * 64 + l];

    // ---- A fragments: interpolated anchor features, channels ks*32+q*8..+7 ----
    f16x8 A1[2];
    #pragma unroll
    for (int ks = 0; ks < 2; ++ks) {
        const int ch = ks * 32 + q * 8;
        float4 u0 = *(const float4*)(f0p + ch);
        float4 v0 = *(const float4*)(f1p + ch);
        float4 u1 = *(const float4*)(f0p + ch + 4);
        float4 v1 = *(const float4*)(f1p + ch + 4);
        A1[ks][0] = (f16)fmaf(w, v0.x - u0.x, u0.x);
        A1[ks][1] = (f16)fmaf(w, v0.y - u0.y, u0.y);
        A1[ks][2] = (f16)fmaf(w, v0.z - u0.z, u0.z);
        A1[ks][3] = (f16)fmaf(w, v0.w - u0.w, u0.w);
        A1[ks][4] = (f16)fmaf(w, v1.x - u1.x, u1.x);
        A1[ks][5] = (f16)fmaf(w, v1.y - u1.y, u1.y);
        A1[ks][6] = (f16)fmaf(w, v1.z - u1.z, u1.z);
        A1[ks][7] = (f16)fmaf(w, v1.w - u1.w, u1.w);
    }

    // ---- layer 1: C init = b1 + cx*W1[64] (the coord input row), then MFMA ----
    float cxr[4];
    #pragma unroll
    for (int reg = 0; reg < 4; ++reg) cxr[reg] = coords[p0 + q * 4 + reg];

    f32x4 Ch[4];
    #pragma unroll
    for (int nt = 0; nt < 4; ++nt) {
        const int hc = nt * 16 + col;
        const float bb = b1[hc];
        const float wl = W1[64 * 64 + hc];
        #pragma unroll
        for (int reg = 0; reg < 4; ++reg) Ch[nt][reg] = fmaf(cxr[reg], wl, bb);
    }
    #pragma unroll
    for (int nt = 0; nt < 4; ++nt)
        #pragma unroll
        for (int ks = 0; ks < 2; ++ks)
            Ch[nt] = mfma16(A1[ks], wb1[nt][ks], Ch[nt]);

    // ---- leaky -> a (keep C-layout copy), stage a to LDS f16 ----
    #pragma unroll
    for (int nt = 0; nt < 4; ++nt)
        #pragma unroll
        for (int reg = 0; reg < 4; ++reg) {
            float hv = Ch[nt][reg];
            float av = hv >= 0.0f ? hv : NEG * hv;
            Ch[nt][reg] = av;
            a_tile[wv][q * 4 + reg][nt * 16 + col] = (f16)av;
        }

    // ---- residual: Cg = a + br + a@Wr, leaky, restage g ----
    const f16x8* Wrp = (const f16x8*)Wrf;
    f16x8 wbr[4][2];
    #pragma unroll
    for (int nt = 0; nt < 4; ++nt)
        #pragma unroll
        for (int ks = 0; ks < 2; ++ks)
            wbr[nt][ks] = Wrp[(nt * 2 + ks) * 64 + l];

    f16x8 Ar[2];
    #pragma unroll
    for (int ks = 0; ks < 2; ++ks)
        Ar[ks] = *(const f16x8*)&a_tile[wv][r][ks * 32 + q * 8];

    f32x4 Cg[4];
    #pragma unroll
    for (int nt = 0; nt < 4; ++nt) {
        const float bb = br[nt * 16 + col];
        #pragma unroll
        for (int reg = 0; reg < 4; ++reg) Cg[nt][reg] = Ch[nt][reg] + bb;
        #pragma unroll
        for (int ks = 0; ks < 2; ++ks)
            Cg[nt] = mfma16(Ar[ks], wbr[nt][ks], Cg[nt]);
        #pragma unroll
        for (int reg = 0; reg < 4; ++reg) {
            float gv = Cg[nt][reg];
            gv = gv >= 0.0f ? gv : NEG * gv;
            a_tile[wv][q * 4 + reg][nt * 16 + col] = (f16)gv;  // anti-dep after Ar reads
        }
    }

    // ---- layer 3: o = g @ W2pad + b2 (N=16 tile, cols 0..9 valid) ----
    const f16x8* W2p = (const f16x8*)W2f;
    f16x8 Ag[2];
    #pragma unroll
    for (int ks = 0; ks < 2; ++ks)
        Ag[ks] = *(const f16x8*)&a_tile[wv][r][ks * 32 + q * 8];

    const float b2v = (col < 10) ? b2[col] : 0.0f;
    f32x4 Co;
    #pragma unroll
    for (int reg = 0; reg < 4; ++reg) Co[reg] = b2v;
    #pragma unroll
    for (int ks = 0; ks < 2; ++ks)
        Co = mfma16(Ag[ks], W2p[ks * 64 + l], Co);

    // ---- epilogue: per point-row softmax (cols 5..9) + tanh offsets (cols 0..4) ----
    const float maxoff = 6.0f / 4096.0f;
    const bool isSm = (col >= 5 && col < 10);
    #pragma unroll
    for (int reg = 0; reg < 4; ++reg) {
        const float ov = Co[reg];
        float m = isSm ? ov : -1e30f;
        #pragma unroll
        for (int d = 1; d < 16; d <<= 1) m = fmaxf(m, __shfl_xor(m, d, 16));
        float e = isSm ? __expf(ov - m) : 0.0f;
        float s = e;
        #pragma unroll
        for (int d = 1; d < 16; d <<= 1) s += __shfl_xor(s, d, 16);
        const int pr = q * 4 + reg;
        if (col < 5) {
            float ax = fabsf(ov);
            float t = __expf(-2.0f * ax);
            float th = (1.0f - t) / (1.0f + t);
            offs_t[wv][pr][col] = copysignf(th, ov) * maxoff;
        } else if (col < 10) {
            wk_t[wv][pr][col - 5] = e / s;
        }
    }

    // ---- aggregation: lane (r, q) -> point p0+r, channels q*16..+15 ----
    float po[5], pw[5];
    #pragma unroll
    for (int k = 0; k < 5; ++k) { po[k] = offs_t[wv][r][k]; pw[k] = wk_t[wv][r][k]; }

    float acc[16];
    #pragma unroll
    for (int c = 0; c < 16; ++c) acc[c] = 0.0f;

    #pragma unroll
    for (int k = 0; k < 5; ++k) {
        float dx = cx + po[k];
        float xq = fminf(fmaxf((dx + 1.0f) * 0.5f * 4095.0f, 0.0f), 4095.0f);
        float xq0 = floorf(xq);
        float wq = xq - xq0;
        int j0 = (int)xq0;
        int j1 = min(j0 + 1, 4095);
        const float* g0 = featT + (((size_t)b * L_ + j0) << 6) + q * 16;
        const float* g1 = featT + (((size_t)b * L_ + j1) << 6) + q * 16;
        const float wkk = pw[k];
        #pragma unroll
        for (int c4 = 0; c4 < 16; c4 += 4) {
            float4 u = *(const float4*)(g0 + c4);
            float4 v = *(const float4*)(g1 + c4);
            acc[c4 + 0] = fmaf(wkk, fmaf(wq, v.x - u.x, u.x), acc[c4 + 0]);
            acc[c4 + 1] = fmaf(wkk, fmaf(wq, v.y - u.y, u.y), acc[c4 + 1]);
            acc[c4 + 2] = fmaf(wkk, fmaf(wq, v.z - u.z, u.z), acc[c4 + 2]);
            acc[c4 + 3] = fmaf(wkk, fmaf(wq, v.w - u.w, u.w), acc[c4 + 3]);
        }
    }

    float* op = out + ((size_t)p << 6) + q * 16;
    #pragma unroll
    for (int c4 = 0; c4 < 16; c4 += 4)
        *(float4*)(op + c4) = make_float4(acc[c4], acc[c4 + 1], acc[c4 + 2], acc[c4 + 3]);
}

extern "C" void kernel_launch(void* const* d_in, const int* in_sizes, int n_in,
                              void* d_out, int out_size, void* d_ws, size_t ws_size,
                              hipStream_t stream) {
    const float* feat   = (const float*)d_in[0];
    const float* coords = (const float*)d_in[1];
    const float* W1 = (const float*)d_in[2];
    const float* b1 = (const float*)d_in[3];
    const float* Wr = (const float*)d_in[4];
    const float* br = (const float*)d_in[5];
    const float* W2 = (const float*)d_in[6];
    const float* b2 = (const float*)d_in[7];
    float* out = (float*)d_out;

    float* featT = (float*)d_ws;                       // 4 MiB
    f16* W1f = (f16*)((char*)d_ws + (4u << 20));       // 8 KiB
    f16* Wrf = W1f + 4096;                             // 8 KiB
    f16* W2f = Wrf + 4096;                             // 2 KiB

    hipLaunchKernelGGL(transpose_feat, dim3(L_ / 64, B_), dim3(256), 0, stream, feat, featT);
    hipLaunchKernelGGL(pack_weights, dim3(16), dim3(256), 0, stream, W1, Wr, W2, W1f, Wrf, W2f);
    hipLaunchKernelGGL(deform_mfma, dim3(P_ / 64), dim3(256), 0, stream,
                       featT, coords, W1f, Wrf, W2f, W1, b1, br, b2, out);
}

// Round 3
// 196.987 us; speedup vs baseline: 2.3190x; 1.4459x over previous
//
#include <hip/hip_runtime.h>
#include <hip/hip_fp16.h>
#include <math.h>

typedef _Float16 f16;
typedef f16 f16x8 __attribute__((ext_vector_type(8)));
typedef float f32x4 __attribute__((ext_vector_type(4)));

#define B_ 4
#define C_ 64
#define L_ 4096
#define N_ 100000
#define P_ (B_ * N_)
#define NEG 0.2f

static __device__ __forceinline__ f32x4 mfma16(f16x8 a, f16x8 b, f32x4 c) {
    return __builtin_amdgcn_mfma_f32_16x16x32_f16(a, b, c, 0, 0, 0);
}
static __device__ __forceinline__ f16x8 splat8(f16 x) {
    f16x8 v = {x, x, x, x, x, x, x, x};
    return v;
}

// ---------- kernel 1: transpose feat (B,C,L) f32 -> (B,L,C) f16 ----------
__global__ void transpose_feat(const float* __restrict__ src, f16* __restrict__ dst) {
    __shared__ float tile[64][65];
    const int b  = blockIdx.y;
    const int l0 = blockIdx.x * 64;
    const int tx = threadIdx.x & 63;
    const int ty = threadIdx.x >> 6;   // 0..3
    const size_t base = (size_t)b * C_ * L_;
    #pragma unroll
    for (int cc = ty; cc < 64; cc += 4)
        tile[cc][tx] = src[base + (size_t)cc * L_ + l0 + tx];
    __syncthreads();
    #pragma unroll
    for (int ll = ty; ll < 64; ll += 4)
        dst[base + (size_t)(l0 + ll) * C_ + tx] = (f16)tile[tx][ll];
}

// ---------- kernel 2: pack W1/Wr/W2 into per-lane f16 MFMA B-fragments ----------
__global__ void pack_weights(const float* __restrict__ W1, const float* __restrict__ Wr,
                             const float* __restrict__ W2,
                             f16* __restrict__ W1f, f16* __restrict__ Wrf, f16* __restrict__ W2f) {
    int i = blockIdx.x * 256 + threadIdx.x;
    if (i < 4096) {
        int e = i & 7, lane = (i >> 3) & 63, ks = (i >> 9) & 1, nt = i >> 10;
        int k = ks * 32 + (lane >> 4) * 8 + e;
        int c = nt * 16 + (lane & 15);
        W1f[i] = (f16)W1[k * 64 + c];
        Wrf[i] = (f16)Wr[k * 64 + c];
    }
    if (i < 1024) {                       // W2 padded 64x10 -> 64x16
        int e = i & 7, lane = (i >> 3) & 63, ks = (i >> 9) & 1;
        int k = ks * 32 + (lane >> 4) * 8 + e;
        int c = lane & 15;
        W2f[i] = (c < 10) ? (f16)W2[k * 10 + c] : (f16)0.0f;
    }
}

// ---------- kernel 3: router MLP via MFMA; writes (xq, wk) per (point, tap) ----------
// one wave = 16 points. A-layout: lane -> row r=l&15, k=(l>>4)*8+e.
// C-layout (HW-verified): lane -> col=l&15, rows=(l>>4)*4+reg.
__global__ __launch_bounds__(256) void mlp_mfma(
    const f16* __restrict__ featT, const float* __restrict__ coords,
    const f16* __restrict__ W1f, const f16* __restrict__ Wrf, const f16* __restrict__ W2f,
    const float* __restrict__ W1, const float* __restrict__ b1,
    const float* __restrict__ br, const float* __restrict__ b2,
    float* __restrict__ fpw)
{
    __shared__ __align__(16) f16 a_tile[4][16][72];   // per-wave staging, no barriers needed

    const int tid = threadIdx.x;
    const int wv  = tid >> 6;
    const int l   = tid & 63;
    const int r   = l & 15;          // A-role point row
    const int q   = l >> 4;          // A-role k-group / C-role row quarter
    const int col = l & 15;          // C-role column
    const int p0  = (blockIdx.x * 4 + wv) * 16;
    const int p   = p0 + r;
    const int b   = p / N_;

    // ---- anchor position for this lane's A-role point ----
    const float cx = coords[p];
    float xp = fminf(fmaxf((cx + 1.0f) * 0.5f * 4095.0f, 0.0f), 4095.0f);
    float x0f = floorf(xp);
    float w = xp - x0f;
    int i0 = (int)x0f;
    int i1 = min(i0 + 1, 4095);
    const f16* f0p = featT + (((size_t)b * L_ + i0) << 6);
    const f16* f1p = featT + (((size_t)b * L_ + i1) << 6);

    // ---- W1 fragments ----
    const f16x8* W1p = (const f16x8*)W1f;
    f16x8 wb1[4][2];
    #pragma unroll
    for (int nt = 0; nt < 4; ++nt)
        #pragma unroll
        for (int ks = 0; ks < 2; ++ks)
            wb1[nt][ks] = W1p[(nt * 2 + ks) * 64 + l];

    // ---- A fragments: packed-f16 interpolated anchor features ----
    const f16 wh = (f16)w;
    f16x8 A1[2];
    #pragma unroll
    for (int ks = 0; ks < 2; ++ks) {
        const int ch = ks * 32 + q * 8;
        f16x8 u = *(const f16x8*)(f0p + ch);
        f16x8 v = *(const f16x8*)(f1p + ch);
        A1[ks] = u + splat8(wh) * (v - u);
    }

    // ---- layer 1: C init = b1 + cx*W1[64], then MFMA ----
    float cxr[4];
    #pragma unroll
    for (int reg = 0; reg < 4; ++reg) cxr[reg] = coords[p0 + q * 4 + reg];

    f32x4 Ch[4];
    #pragma unroll
    for (int nt = 0; nt < 4; ++nt) {
        const int hc = nt * 16 + col;
        const float bb = b1[hc];
        const float wl = W1[64 * 64 + hc];
        #pragma unroll
        for (int reg = 0; reg < 4; ++reg) Ch[nt][reg] = fmaf(cxr[reg], wl, bb);
    }
    #pragma unroll
    for (int nt = 0; nt < 4; ++nt)
        #pragma unroll
        for (int ks = 0; ks < 2; ++ks)
            Ch[nt] = mfma16(A1[ks], wb1[nt][ks], Ch[nt]);

    // ---- leaky -> a; stage to LDS ----
    #pragma unroll
    for (int nt = 0; nt < 4; ++nt)
        #pragma unroll
        for (int reg = 0; reg < 4; ++reg) {
            float hv = Ch[nt][reg];
            float av = hv >= 0.0f ? hv : NEG * hv;
            Ch[nt][reg] = av;
            a_tile[wv][q * 4 + reg][nt * 16 + col] = (f16)av;
        }

    // ---- residual: g = leaky(a + br + a@Wr), restage ----
    const f16x8* Wrp = (const f16x8*)Wrf;
    f16x8 wbr[4][2];
    #pragma unroll
    for (int nt = 0; nt < 4; ++nt)
        #pragma unroll
        for (int ks = 0; ks < 2; ++ks)
            wbr[nt][ks] = Wrp[(nt * 2 + ks) * 64 + l];

    f16x8 Ar[2];
    #pragma unroll
    for (int ks = 0; ks < 2; ++ks)
        Ar[ks] = *(const f16x8*)&a_tile[wv][r][ks * 32 + q * 8];

    f32x4 Cg[4];
    #pragma unroll
    for (int nt = 0; nt < 4; ++nt) {
        const float bb = br[nt * 16 + col];
        #pragma unroll
        for (int reg = 0; reg < 4; ++reg) Cg[nt][reg] = Ch[nt][reg] + bb;
        #pragma unroll
        for (int ks = 0; ks < 2; ++ks)
            Cg[nt] = mfma16(Ar[ks], wbr[nt][ks], Cg[nt]);
        #pragma unroll
        for (int reg = 0; reg < 4; ++reg) {
            float gv = Cg[nt][reg];
            gv = gv >= 0.0f ? gv : NEG * gv;
            a_tile[wv][q * 4 + reg][nt * 16 + col] = (f16)gv;
        }
    }

    // ---- layer 3: o = g @ W2pad + b2 ----
    const f16x8* W2p = (const f16x8*)W2f;
    f16x8 Ag[2];
    #pragma unroll
    for (int ks = 0; ks < 2; ++ks)
        Ag[ks] = *(const f16x8*)&a_tile[wv][r][ks * 32 + q * 8];

    const float b2v = (col < 10) ? b2[col] : 0.0f;
    f32x4 Co;
    #pragma unroll
    for (int reg = 0; reg < 4; ++reg) Co[reg] = b2v;
    #pragma unroll
    for (int ks = 0; ks < 2; ++ks)
        Co = mfma16(Ag[ks], W2p[ks * 64 + l], Co);

    // ---- epilogue: tanh offsets -> deformed coordinate xq; softmax -> wk ----
    const float maxoff = 6.0f / 4096.0f;
    const bool isSm = (col >= 5 && col < 10);
    #pragma unroll
    for (int reg = 0; reg < 4; ++reg) {
        const float ov = Co[reg];
        float m = isSm ? ov : -1e30f;
        #pragma unroll
        for (int d = 1; d < 16; d <<= 1) m = fmaxf(m, __shfl_xor(m, d, 16));
        float e = isSm ? __expf(ov - m) : 0.0f;
        float s = e;
        #pragma unroll
        for (int d = 1; d < 16; d <<= 1) s += __shfl_xor(s, d, 16);
        const int pr = q * 4 + reg;          // point row this reg belongs to
        const size_t pt = (size_t)(p0 + pr);
        if (col < 5) {
            float ax = fabsf(ov);
            float t = __expf(-2.0f * ax);
            float th = (1.0f - t) / (1.0f + t);
            float off = copysignf(th, ov) * maxoff;
            float dx = cxr[reg] + off;
            float xq = fminf(fmaxf((dx + 1.0f) * 0.5f * 4095.0f, 0.0f), 4095.0f);
            fpw[(pt * 5 + col) * 2 + 0] = xq;
        } else if (col < 10) {
            fpw[(pt * 5 + (col - 5)) * 2 + 1] = e / s;
        }
    }
}

// ---------- kernel 4: streaming gather + weighted aggregation ----------
// 4 lanes per point, 16 channels each; no LDS; packed-f16 math.
__global__ __launch_bounds__(256) void deform_agg(
    const f16* __restrict__ featT, const float* __restrict__ fpw,
    float* __restrict__ out)
{
    const int idx = blockIdx.x * 256 + threadIdx.x;
    const int p = idx >> 2;
    const int q = idx & 3;
    const int b = p / N_;
    const size_t fb = (size_t)b * L_;

    float xq[5], wk[5];
    const float* t = fpw + (size_t)p * 10;
    #pragma unroll
    for (int k = 0; k < 5; ++k) { xq[k] = t[2 * k]; wk[k] = t[2 * k + 1]; }

    f16x8 acc0 = splat8((f16)0.0f);
    f16x8 acc1 = splat8((f16)0.0f);

    #pragma unroll
    for (int k = 0; k < 5; ++k) {
        float x0f = floorf(xq[k]);
        float wq = xq[k] - x0f;
        int j0 = (int)x0f;
        int j1 = min(j0 + 1, 4095);
        const f16* g0 = featT + ((fb + j0) << 6) + q * 16;
        const f16* g1 = featT + ((fb + j1) << 6) + q * 16;
        f16x8 u0 = *(const f16x8*)g0;
        f16x8 u1 = *(const f16x8*)(g0 + 8);
        f16x8 v0 = *(const f16x8*)g1;
        f16x8 v1 = *(const f16x8*)(g1 + 8);
        f16x8 wqv = splat8((f16)wq);
        f16x8 wkv = splat8((f16)wk[k]);
        acc0 += wkv * (u0 + wqv * (v0 - u0));
        acc1 += wkv * (u1 + wqv * (v1 - u1));
    }

    float* op = out + ((size_t)p << 6) + q * 16;
    *(float4*)(op + 0)  = make_float4((float)acc0[0], (float)acc0[1], (float)acc0[2], (float)acc0[3]);
    *(float4*)(op + 4)  = make_float4((float)acc0[4], (float)acc0[5], (float)acc0[6], (float)acc0[7]);
    *(float4*)(op + 8)  = make_float4((float)acc1[0], (float)acc1[1], (float)acc1[2], (float)acc1[3]);
    *(float4*)(op + 12) = make_float4((float)acc1[4], (float)acc1[5], (float)acc1[6], (float)acc1[7]);
}

extern "C" void kernel_launch(void* const* d_in, const int* in_sizes, int n_in,
                              void* d_out, int out_size, void* d_ws, size_t ws_size,
                              hipStream_t stream) {
    const float* feat   = (const float*)d_in[0];
    const float* coords = (const float*)d_in[1];
    const float* W1 = (const float*)d_in[2];
    const float* b1 = (const float*)d_in[3];
    const float* Wr = (const float*)d_in[4];
    const float* br = (const float*)d_in[5];
    const float* W2 = (const float*)d_in[6];
    const float* b2 = (const float*)d_in[7];
    float* out = (float*)d_out;

    f16*   featT = (f16*)d_ws;                                 // 2 MiB
    f16*   W1f   = (f16*)((char*)d_ws + (2u << 20));           // 8 KiB
    f16*   Wrf   = W1f + 4096;                                 // 8 KiB
    f16*   W2f   = Wrf + 4096;                                 // 2 KiB
    float* fpw   = (float*)((char*)d_ws + (3u << 20));         // 16 MiB: (xq,wk) x 5 per point

    hipLaunchKernelGGL(transpose_feat, dim3(L_ / 64, B_), dim3(256), 0, stream, feat, featT);
    hipLaunchKernelGGL(pack_weights, dim3(16), dim3(256), 0, stream, W1, Wr, W2, W1f, Wrf, W2f);
    hipLaunchKernelGGL(mlp_mfma, dim3(P_ / 64), dim3(256), 0, stream,
                       featT, coords, W1f, Wrf, W2f, W1, b1, br, b2, fpw);
    hipLaunchKernelGGL(deform_agg, dim3(P_ * 4 / 256), dim3(256), 0, stream,
                       featT, fpw, out);
}